// Round 1
// baseline (91.790 us; speedup 1.0000x reference)
//
#include <hip/hip_runtime.h>
#include <math.h>

#define NR 24
#define NBATCH 2
#define NFEAT 2
#define NX 256
#define NY 256
#define NZ 16

// np.pi as double (nearest double to pi)
constexpr double DPI = 3.141592653589793;

struct Tgts { float t[NR]; int neg[NR]; };

constexpr Tgts make_tgts() {
    Tgts r{};
    for (int i = 0; i < NR; ++i) {
        // identical double arithmetic to: np.arange(24)*(2.0*np.pi/24.0) - np.pi
        double a = (double)i * (2.0 * DPI / 24.0) - DPI;
        int neg = (a > 0.5 * DPI) || (a < -0.5 * DPI);
        double t = a;
        if (a > 0.5 * DPI)       t = a - DPI;
        else if (a < -0.5 * DPI) t = a + DPI;
        r.t[i]   = (float)t;     // matches targets.astype(np.float32)
        r.neg[i] = neg;
    }
    return r;
}
constexpr Tgts TG = make_tgts();

// Kernel 1: per-(bf,row) block. Thread = (col-phase c0, z). Accumulate
// 24 per-radius gaussian-weighted sums, reduce across block, atomicAdd to ws.
__global__ __launch_bounds__(256) void grx_partial(
    const float* __restrict__ x,
    const float* __restrict__ com_real,
    const float* __restrict__ com_imag,
    float* __restrict__ ws)
{
    const int tid = threadIdx.x;
    const int z   = tid & 15;        // 0..15, innermost for coalescing
    const int c0  = tid >> 4;        // 0..15 col phase
    const int row = blockIdx.x & (NX - 1);
    const int bf  = blockIdx.x >> 8; // 0..3

    const float comr = com_real[bf * NZ + z];
    const float comi = com_imag[bf * NZ + z];
    const float dy   = (float)row - comi;   // constant for this thread

    const float KE  = -50.0f;               // -1/(2*sigma^2), sigma=0.1
    const float PIF = 3.14159265358979323846f;

    float acc[NR];
    #pragma unroll
    for (int r = 0; r < NR; ++r) acc[r] = 0.0f;

    const float* xp = x + ((size_t)(bf * NX + row)) * (NY * NZ);

    #pragma unroll 4
    for (int k = 0; k < 16; ++k) {
        const int col  = c0 + (k << 4);
        const float xv = xp[col * NZ + z];           // wave-coalesced
        const float dx = (float)col - comr;
        const float th  = atan2f(dy, dx);
        const float thn = th - copysignf(PIF, th);   // == atan2f(-dy,-dx) up to ~3e-7
        #pragma unroll
        for (int r = 0; r < NR; ++r) {
            const float sel = TG.neg[r] ? thn : th;  // compile-time select
            const float d   = sel - TG.t[r];
            acc[r] += __expf(d * d * KE) * xv;
        }
    }

    // Block reduction: sum over the 16 col phases for each (z, r).
    __shared__ float red[256 * NR];   // 24 KiB
    #pragma unroll
    for (int r = 0; r < NR; ++r) red[tid * NR + r] = acc[r];
    __syncthreads();

    for (int o = tid; o < NR * NZ; o += 256) {
        const int r  = o >> 4;
        const int zz = o & 15;
        float s = 0.0f;
        #pragma unroll
        for (int c = 0; c < 16; ++c)
            s += red[(c * 16 + zz) * NR + r];
        atomicAdd(&ws[(bf * NR + r) * NZ + zz], s);
    }
}

// Kernel 2: out = sqrt(2*s), with coef folded in during accumulation? No —
// coef is folded here: s_true = coef * ws, out = sqrt(2*coef*ws).
__global__ void grx_finalize(const float* __restrict__ ws, float* __restrict__ out, int n)
{
    const int i = blockIdx.x * blockDim.x + threadIdx.x;
    if (i < n) {
        // coef = 1/(sigma*sqrt(2*pi))
        const float coef = 3.9894228040143270f;
        out[i] = sqrtf(2.0f * coef * ws[i]);
    }
}

extern "C" void kernel_launch(void* const* d_in, const int* in_sizes, int n_in,
                              void* d_out, int out_size, void* d_ws, size_t ws_size,
                              hipStream_t stream)
{
    const float* x  = (const float*)d_in[0];
    const float* cr = (const float*)d_in[1];
    const float* ci = (const float*)d_in[2];
    float* out = (float*)d_out;
    float* ws  = (float*)d_ws;

    const int nout = NBATCH * NFEAT * NR * NZ;   // 1536
    hipMemsetAsync(ws, 0, nout * sizeof(float), stream);

    grx_partial<<<dim3(NBATCH * NFEAT * NX), dim3(256), 0, stream>>>(x, cr, ci, ws);
    grx_finalize<<<dim3((nout + 255) / 256), dim3(256), 0, stream>>>(ws, out, nout);
}

// Round 3
// 90.058 us; speedup vs baseline: 1.0192x; 1.0192x over previous
//
#include <hip/hip_runtime.h>

#define NR 24
#define NBATCH 2
#define NFEAT 2
#define NX 256
#define NY 256
#define NZ 16
#define PAD 25   // 24 slots + 1 pad: odd stride -> conflict-free-ish dynamic LDS banking

// Per (bf,row,col-half) block. Thread = (col-phase c0, z).
// Circular-binning: each pixel hits only 3 of 24 radii (sigma=0.1 << spacing 0.262).
__global__ __launch_bounds__(256) void grx_partial(
    const float* __restrict__ x,
    const float* __restrict__ com_real,
    const float* __restrict__ com_imag,
    float* __restrict__ ws)
{
    __shared__ float red[256 * PAD];   // 25.6 KiB -> 6 blocks/CU by LDS

    const int tid  = threadIdx.x;
    const int z    = tid & 15;
    const int c0   = tid >> 4;
    const int half = blockIdx.x & 1;           // which 8-column group
    const int row  = (blockIdx.x >> 1) & (NX - 1);
    const int bf   = blockIdx.x >> 9;          // 0..3

    // zero my private accumulator row (no sync needed: private until reduction)
    float* myred = &red[tid * PAD];
    #pragma unroll
    for (int i = 0; i < PAD; ++i) myred[i] = 0.0f;

    const float comr = com_real[bf * NZ + z];
    const float comi = com_imag[bf * NZ + z];
    const float dyv  = (float)row - comi;      // constant for this thread
    const float ady  = fabsf(dyv);

    const float PIF   = 3.14159265358979f;
    const float PI_2  = 1.57079632679490f;
    const float C_PSI = 3.81971863420549f;     // 12/pi
    const float C_E   = -3.4269908169872414f;  // -50*(pi/12)^2  (natural log scale)

    const float* xp = x + ((size_t)(bf * NX + row)) * (NY * NZ);

    #pragma unroll 2
    for (int kk = 0; kk < 8; ++kk) {
        const int col  = c0 + ((half * 8 + kk) << 4);
        const float xv = xp[col * NZ + z];      // 64 consecutive floats per wave
        const float dxv = (float)col - comr;

        // ---- custom atan2 (|err| ~1e-5 rad; tolerance allows ~1e-3) ----
        const float adx = fabsf(dxv);
        const float mn  = fminf(adx, ady);
        const float mx  = fmaxf(adx, ady);
        const float t   = mn * __builtin_amdgcn_rcpf(fmaxf(mx, 1e-30f));  // [0,1]
        const float r2  = t * t;
        float p = fmaf(r2, 0.0208351f, -0.0851330f);
        p = fmaf(r2, p, 0.1801410f);
        p = fmaf(r2, p, -0.3302995f);
        p = fmaf(r2, p, 0.9998660f);
        float th = t * p;
        if (ady > adx)  th = PI_2 - th;
        if (dxv < 0.0f) th = PIF - th;
        th = copysignf(th, dyv);

        // ---- circular binning: 3 neighbors on the 24-bin circle ----
        const float psi = th * C_PSI;          // (-12, 12]
        const float nf  = rintf(psi);          // v_rndne
        const float f   = psi - nf;            // [-0.5, 0.5]
        const int base  = (int)nf + 12;        // [0, 24]

        const float fm = f + 1.0f;
        const float fp = f - 1.0f;
        const float w0 = __expf(C_E * f  * f ) * xv;
        const float wm = __expf(C_E * fm * fm) * xv;
        const float wp = __expf(C_E * fp * fp) * xv;

        int v0 = base - 1; v0 = (v0 < 0)   ? v0 + 24 : v0;
        int v1 = base;     v1 = (v1 >= 24) ? v1 - 24 : v1;
        int v2 = base + 1; v2 = (v2 >= 24) ? v2 - 24 : v2;

        myred[v0] += wm;
        myred[v1] += w0;
        myred[v2] += wp;
    }

    __syncthreads();

    // Reduce over the 16 col-phases for each (radius, z); one atomic per (r,z).
    for (int o = tid; o < NR * NZ; o += 256) {
        const int r  = o >> 4;
        const int zz = o & 15;
        float s = 0.0f;
        #pragma unroll
        for (int c = 0; c < 16; ++c)
            s += red[(c * 16 + zz) * PAD + r];
        atomicAdd(&ws[(bf * NR + r) * NZ + zz], s);
    }
}

__global__ void grx_finalize(const float* __restrict__ ws, float* __restrict__ out, int n)
{
    const int i = blockIdx.x * blockDim.x + threadIdx.x;
    if (i < n) {
        const float coef = 3.9894228040143270f;   // 1/(sigma*sqrt(2*pi))
        out[i] = sqrtf(2.0f * coef * ws[i]);
    }
}

extern "C" void kernel_launch(void* const* d_in, const int* in_sizes, int n_in,
                              void* d_out, int out_size, void* d_ws, size_t ws_size,
                              hipStream_t stream)
{
    const float* x  = (const float*)d_in[0];
    const float* cr = (const float*)d_in[1];
    const float* ci = (const float*)d_in[2];
    float* out = (float*)d_out;
    float* ws  = (float*)d_ws;

    const int nout = NBATCH * NFEAT * NR * NZ;   // 1536
    (void)hipMemsetAsync(ws, 0, nout * sizeof(float), stream);

    grx_partial<<<dim3(NBATCH * NFEAT * NX * 2), dim3(256), 0, stream>>>(x, cr, ci, ws);
    grx_finalize<<<dim3((nout + 255) / 256), dim3(256), 0, stream>>>(ws, out, nout);
}

// Round 4
// 78.833 us; speedup vs baseline: 1.1644x; 1.1424x over previous
//
#include <hip/hip_runtime.h>

#define NR 24
#define NBATCH 2
#define NFEAT 2
#define NX 256
#define NY 256
#define NZ 16
#define PAD 25            // 24 slots + 1 pad: odd stride -> 2-way (free) LDS banking
#define NBLK_PER_BF 512   // 256 rows x 2 col-halves
#define NPART (NR * NZ)   // 384 partials per block

// Stage 1: per (bf,row,col-half) block. Thread = (col-phase c0, z).
// Circular binning: each pixel hits only 3 of 24 radii (sigma=0.1 << spacing 0.262).
// Writes per-block partials NON-atomically: ws[blk*384 + (r*16+z)].
__global__ __launch_bounds__(256) void grx_partial(
    const float* __restrict__ x,
    const float* __restrict__ com_real,
    const float* __restrict__ com_imag,
    float* __restrict__ ws)
{
    __shared__ float red[256 * PAD];   // 25.6 KiB

    const int tid  = threadIdx.x;
    const int z    = tid & 15;
    const int c0   = tid >> 4;
    const int half = blockIdx.x & 1;
    const int row  = (blockIdx.x >> 1) & (NX - 1);
    const int bf   = blockIdx.x >> 9;          // 0..3

    float* myred = &red[tid * PAD];
    #pragma unroll
    for (int i = 0; i < PAD; ++i) myred[i] = 0.0f;

    const float comr = com_real[bf * NZ + z];
    const float comi = com_imag[bf * NZ + z];
    const float dyv  = (float)row - comi;
    const float ady  = fabsf(dyv);

    const float PIF   = 3.14159265358979f;
    const float PI_2  = 1.57079632679490f;
    const float C_PSI = 3.81971863420549f;     // 12/pi
    const float C_E   = -3.4269908169872414f;  // -50*(pi/12)^2

    const float* xp = x + ((size_t)(bf * NX + row)) * (NY * NZ);

    #pragma unroll 2
    for (int kk = 0; kk < 8; ++kk) {
        const int col  = c0 + ((half * 8 + kk) << 4);
        const float xv = xp[col * NZ + z];      // 64 consecutive floats per wave
        const float dxv = (float)col - comr;

        // ---- custom atan2 (|err| ~1e-5 rad) ----
        const float adx = fabsf(dxv);
        const float mn  = fminf(adx, ady);
        const float mx  = fmaxf(adx, ady);
        const float t   = mn * __builtin_amdgcn_rcpf(fmaxf(mx, 1e-30f));
        const float r2  = t * t;
        float p = fmaf(r2, 0.0208351f, -0.0851330f);
        p = fmaf(r2, p, 0.1801410f);
        p = fmaf(r2, p, -0.3302995f);
        p = fmaf(r2, p, 0.9998660f);
        float th = t * p;
        if (ady > adx)  th = PI_2 - th;
        if (dxv < 0.0f) th = PIF - th;
        th = copysignf(th, dyv);

        // ---- circular binning: 3 neighbors on the 24-bin circle ----
        const float psi = th * C_PSI;
        const float nf  = rintf(psi);
        const float f   = psi - nf;             // [-0.5, 0.5]
        const int base  = (int)nf + 12;         // [0, 24]

        const float fm = f + 1.0f;
        const float fp = f - 1.0f;
        const float w0 = __expf(C_E * f  * f ) * xv;
        const float wm = __expf(C_E * fm * fm) * xv;
        const float wp = __expf(C_E * fp * fp) * xv;

        int v0 = base - 1; v0 = (v0 < 0)   ? v0 + 24 : v0;
        int v1 = base;     v1 = (v1 >= 24) ? v1 - 24 : v1;
        int v2 = base + 1; v2 = (v2 >= 24) ? v2 - 24 : v2;

        myred[v0] += wm;
        myred[v1] += w0;
        myred[v2] += wp;
    }

    __syncthreads();

    // Sum over the 16 col phases; coalesced non-atomic store of 384 partials.
    float* wsb = ws + (size_t)blockIdx.x * NPART;
    for (int o = tid; o < NPART; o += 256) {
        const int r  = o >> 4;
        const int zz = o & 15;
        float s = 0.0f;
        #pragma unroll
        for (int c = 0; c < 16; ++c)
            s += red[(c * 16 + zz) * PAD + r];
        wsb[o] = s;
    }
}

// Stage 2: one block per output element (bf, r, z) = (bf, o).
// Sums the 512 per-block partials of that bf, applies sqrt(2*coef*s).
__global__ __launch_bounds__(256) void grx_reduce(
    const float* __restrict__ ws, float* __restrict__ out)
{
    const int b  = blockIdx.x;          // 0..1535
    const int bf = b / NPART;
    const int o  = b - bf * NPART;
    const int tid = threadIdx.x;

    const float* base = ws + (size_t)bf * NBLK_PER_BF * NPART + o;
    float s = base[(size_t)tid * NPART] + base[(size_t)(tid + 256) * NPART];

    // wave reduce (64 lanes)
    #pragma unroll
    for (int off = 32; off; off >>= 1) s += __shfl_down(s, off, 64);

    __shared__ float w4[4];
    if ((tid & 63) == 0) w4[tid >> 6] = s;
    __syncthreads();
    if (tid == 0) {
        const float coef = 3.9894228040143270f;   // 1/(sigma*sqrt(2*pi))
        const float tot = w4[0] + w4[1] + w4[2] + w4[3];
        out[b] = sqrtf(2.0f * coef * tot);
    }
}

extern "C" void kernel_launch(void* const* d_in, const int* in_sizes, int n_in,
                              void* d_out, int out_size, void* d_ws, size_t ws_size,
                              hipStream_t stream)
{
    const float* x  = (const float*)d_in[0];
    const float* cr = (const float*)d_in[1];
    const float* ci = (const float*)d_in[2];
    float* out = (float*)d_out;
    float* ws  = (float*)d_ws;

    grx_partial<<<dim3(NBATCH * NFEAT * NBLK_PER_BF), dim3(256), 0, stream>>>(x, cr, ci, ws);
    grx_reduce<<<dim3(NBATCH * NFEAT * NPART), dim3(256), 0, stream>>>(ws, out);
}

// Round 5
// 77.110 us; speedup vs baseline: 1.1904x; 1.0223x over previous
//
#include <hip/hip_runtime.h>

#define NR 24
#define NBATCH 2
#define NFEAT 2
#define NX 256
#define NY 256
#define NZ 16
#define PAD 27            // slots -1..25 (no wrap in hot loop) + odd stride -> 2-way-free banks
#define NBLK_PER_BF 512   // 256 rows x 2 col-halves
#define NPART (NR * NZ)   // 384 outputs per bf

// Stage 1: per (bf,row,col-half) block. Thread = (col-phase c0, z).
// Circular binning: each pixel hits only 3 of 24 radii (sigma=0.1 << spacing 0.262).
// Works entirely in "bin units" (theta * 12/pi). 27-slot rows avoid mod-24 wraps.
// Writes partials transposed: ws[(bf*384+o)*512 + local_block].
__global__ __launch_bounds__(256) void grx_partial(
    const float* __restrict__ x,
    const float* __restrict__ com_real,
    const float* __restrict__ com_imag,
    float* __restrict__ ws)
{
    __shared__ float red[256 * PAD];   // 27.6 KiB

    const int tid  = threadIdx.x;
    const int z    = tid & 15;
    const int c0   = tid >> 4;
    const int half = blockIdx.x & 1;
    const int row  = (blockIdx.x >> 1) & (NX - 1);
    const int bf   = blockIdx.x >> 9;          // 0..3

    float* myred = &red[tid * PAD];
    #pragma unroll
    for (int i = 0; i < PAD; ++i) myred[i] = 0.0f;

    const float comr = com_real[bf * NZ + z];
    const float comi = com_imag[bf * NZ + z];
    const float dyv  = (float)row - comi;
    const float ady  = fabsf(dyv);

    // atan poly coefficients pre-scaled by 12/pi (result directly in bin units)
    const float A4 = 0.0795845f;
    const float A3 = -0.3251843f;
    const float A2 = 0.6880875f;
    const float A1 = -1.2616510f;
    const float A0 = 3.8192070f;
    const float C_E = -3.4269908169872414f;    // -50*(pi/12)^2

    const float* xq = x + ((size_t)(bf * NX + row)) * (NY * NZ)
                        + ((c0 + (half << 7)) * NZ + z);
    float dxv = (float)(c0 + (half << 7)) - comr;   // col start; += 16 per iter

    #pragma unroll
    for (int kk = 0; kk < 8; ++kk) {
        const float xv = xq[kk * 256];          // 64 consecutive floats per wave

        // ---- custom atan2 in bin units (|err| ~1e-5 rad equiv) ----
        const float adx = fabsf(dxv);
        const float mn  = fminf(adx, ady);
        const float mx  = fmaxf(adx, ady);
        const float t   = mn * __builtin_amdgcn_rcpf(fmaxf(mx, 1e-30f));
        const float r2  = t * t;
        float p = fmaf(r2, A4, A3);
        p = fmaf(r2, p, A2);
        p = fmaf(r2, p, A1);
        p = fmaf(r2, p, A0);
        float psi = t * p;                      // [0, 6]
        if (ady > adx)  psi = 6.0f - psi;
        if (dxv < 0.0f) psi = 12.0f - psi;
        psi = copysignf(psi, dyv);              // (-12, 12]
        dxv += 16.0f;

        // ---- 3-neighbor circular binning, unwrapped slots ----
        const float nf  = rintf(psi);
        const float f   = psi - nf;             // [-0.5, 0.5]
        const int base  = (int)nf + 12;         // [0, 24] -> slots base..base+2

        const float fm = f + 1.0f;
        const float fp = f - 1.0f;
        const float wm = __expf(C_E * fm * fm) * xv;
        const float w0 = __expf(C_E * f  * f ) * xv;
        const float wp = __expf(C_E * fp * fp) * xv;

        myred[base]     += wm;   // bin base-1
        myred[base + 1] += w0;   // bin base
        myred[base + 2] += wp;   // bin base+1
    }

    __syncthreads();

    // Reduce over 16 col-phases per (r,z); fold wrap slots; transposed store.
    const int l = blockIdx.x & (NBLK_PER_BF - 1);
    for (int o = tid; o < NPART; o += 256) {
        const int r  = o >> 4;
        const int zz = o & 15;
        float s = 0.0f;
        #pragma unroll
        for (int c = 0; c < 16; ++c) {
            const float* rr = &red[(c * 16 + zz) * PAD];
            float v = rr[r + 1];                // slot r+1 holds bin r
            if (r == 0)  v += rr[25];           // bin 24 == 0
            if (r == 1)  v += rr[26];           // bin 25 == 1
            if (r == 23) v += rr[0];            // bin -1 == 23
            s += v;
        }
        ws[((size_t)(bf * NPART + o) * NBLK_PER_BF) + l] = s;
    }
}

// Stage 2: one block per output element; contiguous 512-float run, wave reduce.
__global__ __launch_bounds__(256) void grx_reduce(
    const float* __restrict__ ws, float* __restrict__ out)
{
    const int b   = blockIdx.x;          // 0..1535
    const int tid = threadIdx.x;
    const float* base = ws + (size_t)b * NBLK_PER_BF;
    float s = base[tid] + base[tid + 256];

    #pragma unroll
    for (int off = 32; off; off >>= 1) s += __shfl_down(s, off, 64);

    __shared__ float w4[4];
    if ((tid & 63) == 0) w4[tid >> 6] = s;
    __syncthreads();
    if (tid == 0) {
        // 2 * 1/(sigma*sqrt(2*pi))
        out[b] = sqrtf(7.9788456080286535f * (w4[0] + w4[1] + w4[2] + w4[3]));
    }
}

extern "C" void kernel_launch(void* const* d_in, const int* in_sizes, int n_in,
                              void* d_out, int out_size, void* d_ws, size_t ws_size,
                              hipStream_t stream)
{
    const float* x  = (const float*)d_in[0];
    const float* cr = (const float*)d_in[1];
    const float* ci = (const float*)d_in[2];
    float* out = (float*)d_out;
    float* ws  = (float*)d_ws;

    grx_partial<<<dim3(NBATCH * NFEAT * NBLK_PER_BF), dim3(256), 0, stream>>>(x, cr, ci, ws);
    grx_reduce<<<dim3(NBATCH * NFEAT * NPART), dim3(256), 0, stream>>>(ws, out);
}